// Round 11
// baseline (668.310 us; speedup 1.0000x reference)
//
#include <hip/hip_runtime.h>

// ImprovedGraphSAGE: 4x SAGEConv(aggr='lstm') on MI355X.
// N=20000 nodes, DEG=16, F_IN=HID=128, OUT=64, E=320000.
//
// R11 = R9 minus the x LDS round-trip:
//   x-part MFMA A-fragments are gathered per-lane DIRECTLY from global xbf
//   (L2-resident, 5MB) with a 2-bank rolling prefetch (lookahead 1 rt-phase),
//   deleting the 40KB xsb staging buffer, its writes, and half of all
//   ds_read_b128 traffic on the shared per-CU LDS port. Loads float across
//   the lgkm-only barrier (no vmcnt drain). Stagger/setprio (R10, neutral)
//   reverted.

#define N_NODES 20000
#define DEG 16
#define NPB 80   // nodes per block
#define RT 5     // row tiles (16 rows each)

typedef __bf16 bf16x8 __attribute__((ext_vector_type(8)));
typedef float f32x4 __attribute__((ext_vector_type(4)));

__device__ inline unsigned short f2bf(float f) {
  unsigned u = __builtin_bit_cast(unsigned, f);
  u += 0x7fffu + ((u >> 16) & 1u);
  return (unsigned short)(u >> 16);
}
__device__ inline float fexp2(float x) {
#if __has_builtin(__builtin_amdgcn_exp2f)
  return __builtin_amdgcn_exp2f(x);
#else
  return exp2f(x);
#endif
}
__device__ inline float frcp(float x) {
#if __has_builtin(__builtin_amdgcn_rcpf)
  return __builtin_amdgcn_rcpf(x);
#else
  return 1.f / x;
#endif
}
__device__ inline float sigm(float x) { return frcp(1.f + fexp2(-1.44269504f * x)); }
__device__ inline float tanh_(float x) { return frcp(1.f + fexp2(-2.88539008f * x)) * 2.f - 1.f; }

// LDS-only barrier: flush LDS ops, sync execution, leave global loads in
// flight (no vmcnt drain); consumers get compiler-counted vmcnt waits.
__device__ inline void barrier_lds() {
  asm volatile("s_waitcnt lgkmcnt(0)\n\ts_barrier" ::: "memory");
}

// ---------------------------------------------------------------------------
// prep: weights fp32 -> bf16 (all 4 layers), bsum = bih + bhh
// ---------------------------------------------------------------------------
__global__ __launch_bounds__(256) void prep_weights(
    const float* __restrict__ Wih, const float* __restrict__ Whh,
    const float* __restrict__ bih, const float* __restrict__ bhh,
    unsigned short* __restrict__ WihB, unsigned short* __restrict__ WhhB,
    float* __restrict__ bsum) {
  int tid = blockIdx.x * 256 + threadIdx.x;  // 0..65535
  float4 a = *(const float4*)(Wih + tid * 4);
  ushort4 o;
  o.x = f2bf(a.x); o.y = f2bf(a.y); o.z = f2bf(a.z); o.w = f2bf(a.w);
  *(ushort4*)(WihB + tid * 4) = o;
  float4 b = *(const float4*)(Whh + tid * 4);
  ushort4 p;
  p.x = f2bf(b.x); p.y = f2bf(b.y); p.z = f2bf(b.z); p.w = f2bf(b.w);
  *(ushort4*)(WhhB + tid * 4) = p;
  if (tid < 2048) bsum[tid] = bih[tid] + bhh[tid];
}

// ---------------------------------------------------------------------------
// cast: xbf = bf16(x)
// ---------------------------------------------------------------------------
__global__ __launch_bounds__(256) void cast_bf(
    const float* __restrict__ x, unsigned short* __restrict__ xb) {
  int tid = blockIdx.x * 256 + threadIdx.x;
  float4 v = *(const float4*)(x + tid * 4);
  ushort4 o;
  o.x = f2bf(v.x); o.y = f2bf(v.y); o.z = f2bf(v.z); o.w = f2bf(v.w);
  *(ushort4*)(xb + tid * 4) = o;
}

// ---------------------------------------------------------------------------
// lstm_fused: WG = 80 nodes, 8 waves; wave w owns gate-cols {g*128 + w*16+l15}.
// Per step t, per row-tile rti (phase p = 5t+rti):
//   issue next phase's x A-frags from global into bank (p+1)&1;
//   x-part MFMA from bank p&1; h-part MFMA from LDS h dbuf;
//   activations; h-write. One lgkm-only barrier per step.
// ---------------------------------------------------------------------------
__global__ __launch_bounds__(512, 2) void lstm_fused(
    const unsigned short* __restrict__ xbf,   // [N][128] bf16
    const int* __restrict__ src,              // [E]
    const unsigned short* __restrict__ WihB,  // [512][128] bf16 (layer slice)
    const unsigned short* __restrict__ WhhB,  // [512][128] bf16
    const float* __restrict__ bsum,           // [512]
    float* __restrict__ agg) {                // [N,128] fp32
  __shared__ __align__(16) unsigned char hbuf[2][NPB * 256];  // h dbuf (40KB)
  __shared__ __align__(16) int idx_s[NPB * DEG];              // [t*80 + node]
  const int tid = threadIdx.x;
  const int lane = tid & 63, w = tid >> 6;
  const int l15 = lane & 15, l4 = lane >> 4;
  const int node0 = blockIdx.x * NPB;
  const int colb = w * 16 + l15;  // this wave-lane's output column (per gate)

  // edge indices: task = node*16 + t  ->  idx_s[t*80 + node]
#pragma unroll
  for (int i = 0; i < 3; ++i) {
    int task = tid + i * 512;
    if (task < NPB * DEG) {
      int node = task >> 4, t = task & 15;
      idx_s[t * NPB + node] = src[node0 * DEG + task];
    }
  }

  // weight B-fragments (bf16): B[k][n] = W[gate*128+colb][k]
  bf16x8 bwx[4][4], bwh[4][4];
  float bs[4];
#pragma unroll
  for (int g = 0; g < 4; ++g) {
#pragma unroll
    for (int kt = 0; kt < 4; ++kt) {
      bwx[g][kt] = *(const bf16x8*)(WihB + (g * 128 + colb) * 128 + kt * 32 + l4 * 8);
      bwh[g][kt] = *(const bf16x8*)(WhhB + (g * 128 + colb) * 128 + kt * 32 + l4 * 8);
    }
    bs[g] = bsum[g * 128 + colb];
  }
  barrier_lds();  // idx_s visible

  float c[RT][4];
#pragma unroll
  for (int rt = 0; rt < RT; ++rt)
#pragma unroll
    for (int r = 0; r < 4; ++r) c[rt][r] = 0.f;

  // x A-fragment banks: lane (l15 -> node-row, l4 -> k-chunk) reads 16B x 4.
  // Bank of phase p = 5t+rti is p&1 = (t+rti)&1 (static under unroll).
  bf16x8 xf[2][4];
#define XISSUE(T2, RT2, B)                                            \
  {                                                                   \
    int row_ = idx_s[(T2) * NPB + (RT2) * 16 + l15];                  \
    const unsigned short* rp_ = xbf + row_ * 128 + l4 * 8;            \
    xf[B][0] = *(const bf16x8*)(rp_);                                 \
    xf[B][1] = *(const bf16x8*)(rp_ + 32);                            \
    xf[B][2] = *(const bf16x8*)(rp_ + 64);                            \
    xf[B][3] = *(const bf16x8*)(rp_ + 96);                            \
  }

  XISSUE(0, 0, 0)  // phase 0 -> bank 0

#pragma unroll 2
  for (int t = 0; t < 16; ++t) {
    const unsigned char* hb = hbuf[(t + 1) & 1];  // == (t-1)&1
    unsigned char* hw = hbuf[t & 1];

#pragma unroll
    for (int rti = 0; rti < RT; ++rti) {
      const int cb = (t + rti) & 1;      // bank holding phase p = 5t+rti
      const int ib = (t + rti + 1) & 1;  // bank for phase p+1

      // issue prefetch for phase p+1 (overwrites consumed bank p-1)
      if (rti < RT - 1) {
        XISSUE(t, rti + 1, ib)
      } else if (t + 1 < 16) {
        XISSUE(t + 1, 0, ib)
      }

      f32x4 acc[4];
#pragma unroll
      for (int g = 0; g < 4; ++g) acc[g] = (f32x4){bs[g], bs[g], bs[g], bs[g]};

      // x-part from global-loaded A-frags (bank cb)
#pragma unroll
      for (int kt = 0; kt < 4; ++kt)
#pragma unroll
        for (int g = 0; g < 4; ++g)
          acc[g] = __builtin_amdgcn_mfma_f32_16x16x32_bf16(xf[cb][kt], bwx[g][kt],
                                                           acc[g], 0, 0, 0);

      // h-part (h == 0 at t==0); XOR on the FULL offset (rule #21)
      if (t > 0) {
        const int m = rti * 16 + l15;
#pragma unroll
        for (int kt = 0; kt < 4; ++kt) {
          int byte = (m * 256 + kt * 64 + l4 * 16) ^ ((m & 7) << 4);
          bf16x8 a = *(const bf16x8*)(hb + byte);
#pragma unroll
          for (int g = 0; g < 4; ++g)
            acc[g] = __builtin_amdgcn_mfma_f32_16x16x32_bf16(a, bwh[g][kt], acc[g],
                                                             0, 0, 0);
        }
      }

      // gates + state update (lane-local; gate tiles share C/D lane mapping)
#pragma unroll
      for (int r = 0; r < 4; ++r) {
        float ig = sigm(acc[0][r]), fg = sigm(acc[1][r]);
        float gg = tanh_(acc[2][r]), og = sigm(acc[3][r]);
        float cn = fg * c[rti][r] + ig * gg;
        c[rti][r] = cn;
        float hv = og * tanh_(cn);
        int mm = rti * 16 + l4 * 4 + r;
        if (t < 15) {
          int byte = (mm * 256 + colb * 2) ^ ((mm & 7) << 4);
          *(__bf16*)(hw + byte) = (__bf16)hv;
        } else {
          agg[(node0 + mm) * 128 + colb] = hv;
        }
      }
    }

    if (t < 15) barrier_lds();  // h_t visible; x loads keep flying
  }
#undef XISSUE
}

// ---------------------------------------------------------------------------
// gemm_out: out[N,NOUT] = agg@Wl.T + bl + x@Wr.T (+resid) (+relu)
// One K=256 GEMM with A = [agg | x], B = [Wl | Wr]. Optionally dual-writes
// bf16 copy (next layer's gather source).
// ---------------------------------------------------------------------------
__global__ __launch_bounds__(256) void gemm_out(
    const float* __restrict__ A1,   // agg [N,128]
    const float* __restrict__ A2,   // x   [N,128]
    const float* __restrict__ Wl, const float* __restrict__ bl,
    const float* __restrict__ Wr,
    const float* __restrict__ resid,    // nullptr or [N,128]
    float* __restrict__ out,
    unsigned short* __restrict__ outbf,  // nullptr or [N,128] bf16
    int NOUT, int do_relu, int Nrows) {
  __shared__ __align__(16) unsigned char As[64 * 512];  // [64 rows][256 bf16], swizzled
  const int tid = threadIdx.x;
  const int lane = tid & 63, w = tid >> 6;
  const int l15 = lane & 15, l4 = lane >> 4;
  const int row0 = blockIdx.x * 64;

#pragma unroll
  for (int i = 0; i < 16; ++i) {
    int flat = i * 1024 + tid * 4;  // 0..16383
    int r = flat >> 8, c = flat & 255;
    int grow = row0 + r;
    float4 v;
    if (grow < Nrows)
      v = (c < 128) ? *(const float4*)(A1 + grow * 128 + c)
                    : *(const float4*)(A2 + grow * 128 + (c - 128));
    else
      v = make_float4(0.f, 0.f, 0.f, 0.f);
    ushort4 b;
    b.x = f2bf(v.x); b.y = f2bf(v.y); b.z = f2bf(v.z); b.w = f2bf(v.w);
    int byte = (r * 512 + c * 2) ^ ((r & 7) << 4);
    *(ushort4*)(As + byte) = b;
  }
  __syncthreads();

  const int colg = blockIdx.y * 64 + w * 16 + l15;
  bf16x8 bw[8];
#pragma unroll
  for (int kt = 0; kt < 8; ++kt) {
    const float* bp = (kt < 4) ? (Wl + colg * 128 + kt * 32 + l4 * 8)
                               : (Wr + colg * 128 + (kt - 4) * 32 + l4 * 8);
    float4 a = *(const float4*)bp;
    float4 b = *(const float4*)(bp + 4);
    bf16x8 v;
    v[0] = (__bf16)a.x; v[1] = (__bf16)a.y; v[2] = (__bf16)a.z; v[3] = (__bf16)a.w;
    v[4] = (__bf16)b.x; v[5] = (__bf16)b.y; v[6] = (__bf16)b.z; v[7] = (__bf16)b.w;
    bw[kt] = v;
  }

  f32x4 acc[4];
#pragma unroll
  for (int rt = 0; rt < 4; ++rt) acc[rt] = (f32x4){0.f, 0.f, 0.f, 0.f};

#pragma unroll
  for (int kt = 0; kt < 8; ++kt) {
#pragma unroll
    for (int rt = 0; rt < 4; ++rt) {
      int m = rt * 16 + l15;
      int byte = (m * 512 + kt * 64 + l4 * 16) ^ ((m & 7) << 4);
      bf16x8 af = *(const bf16x8*)(As + byte);
      acc[rt] = __builtin_amdgcn_mfma_f32_16x16x32_bf16(af, bw[kt], acc[rt], 0, 0, 0);
    }
  }

  const float bias = bl[colg];
#pragma unroll
  for (int rt = 0; rt < 4; ++rt)
#pragma unroll
    for (int r = 0; r < 4; ++r) {
      int grow = row0 + rt * 16 + l4 * 4 + r;
      if (grow < Nrows) {
        float v = acc[rt][r] + bias;
        if (resid) v += resid[grow * 128 + colg];
        if (do_relu) v = fmaxf(v, 0.f);
        out[grow * NOUT + colg] = v;
        if (outbf) outbf[grow * 128 + colg] = f2bf(v);
      }
    }
}

// ---------------------------------------------------------------------------
extern "C" void kernel_launch(void* const* d_in, const int* in_sizes, int n_in,
                              void* d_out, int out_size, void* d_ws, size_t ws_size,
                              hipStream_t stream) {
  const float* X = (const float*)d_in[0];
  const int* src = (const int*)d_in[1];  // edge_index[0] = first E ints
  const float* Wih = (const float*)d_in[2];
  const float* Whh = (const float*)d_in[3];
  const float* bih = (const float*)d_in[4];
  const float* bhh = (const float*)d_in[5];
  const float* Wl123 = (const float*)d_in[6];
  const float* bl123 = (const float*)d_in[7];
  const float* Wr123 = (const float*)d_in[8];
  const float* Wl4 = (const float*)d_in[9];
  const float* bl4 = (const float*)d_in[10];
  const float* Wr4 = (const float*)d_in[11];
  float* out = (float*)d_out;

  char* ws = (char*)d_ws;
  unsigned short* xbf = (unsigned short*)ws;                 // 5.12 MB
  float* agg = (float*)(ws + 5120000);                       // 10.24 MB
  float* xb0 = (float*)(ws + 15360000);                      // 10.24 MB
  float* xb1 = (float*)(ws + 25600000);                      // 10.24 MB
  unsigned short* WihB = (unsigned short*)(ws + 35840000);   // 0.52 MB
  unsigned short* WhhB = (unsigned short*)(ws + 36364288);   // 0.52 MB
  float* bsumW = (float*)(ws + 36888576);                    // 8 KB

  prep_weights<<<dim3(256), 256, 0, stream>>>(Wih, Whh, bih, bhh, WihB, WhhB, bsumW);
  cast_bf<<<dim3(2500), 256, 0, stream>>>(X, xbf);

  const float* xcur = X;
  for (int L = 0; L < 4; ++L) {
    lstm_fused<<<dim3(250), 512, 0, stream>>>(xbf, src, WihB + L * 65536,
                                              WhhB + L * 65536, bsumW + L * 512, agg);
    if (L < 3) {
      float* nxt = (L & 1) ? xb1 : xb0;
      gemm_out<<<dim3(313, 2), 256, 0, stream>>>(agg, xcur, Wl123 + L * 16384,
                                                 bl123 + L * 128, Wr123 + L * 16384,
                                                 (L >= 1) ? xcur : nullptr, nxt, xbf,
                                                 128, 1, N_NODES);
      xcur = nxt;
    } else {
      gemm_out<<<dim3(313, 1), 256, 0, stream>>>(agg, xcur, Wl4, bl4, Wr4, nullptr, out,
                                                 nullptr, 64, 0, N_NODES);
    }
  }
}

// Round 12
// 451.056 us; speedup vs baseline: 1.4817x; 1.4817x over previous
//
#include <hip/hip_runtime.h>

// ImprovedGraphSAGE: 4x SAGEConv(aggr='lstm') on MI355X.
// N=20000 nodes, DEG=16, F_IN=HID=128, OUT=64, E=320000.
//
// R12 = R9 (best: 250 blocks x 80 nodes, coalesced x staging, per-rt pipelined
// step, lgkm-only barriers) + PRE-SCALED WEIGHTS: Wih/Whh/bias rows are scaled
// by -log2(e) (gates i,f,o) / -2*log2(e) (gate g) at prep time, so the
// activation block computes rcp(1+exp2(acc)) with no per-element argument
// scaling (saves ~5-8 VALU/output in the issue-bound recurrence).
// R10 stagger/setprio and R11 direct-gather (both regressions) are absent.

#define N_NODES 20000
#define DEG 16
#define NPB 80   // nodes per block
#define RT 5     // row tiles (16 rows each)

typedef __bf16 bf16x8 __attribute__((ext_vector_type(8)));
typedef float f32x4 __attribute__((ext_vector_type(4)));

__device__ inline unsigned short f2bf(float f) {
  unsigned u = __builtin_bit_cast(unsigned, f);
  u += 0x7fffu + ((u >> 16) & 1u);
  return (unsigned short)(u >> 16);
}
__device__ inline float fexp2(float x) {
#if __has_builtin(__builtin_amdgcn_exp2f)
  return __builtin_amdgcn_exp2f(x);
#else
  return exp2f(x);
#endif
}
__device__ inline float frcp(float x) {
#if __has_builtin(__builtin_amdgcn_rcpf)
  return __builtin_amdgcn_rcpf(x);
#else
  return 1.f / x;
#endif
}

// LDS-only barrier: flush LDS ops, sync execution, leave global loads in
// flight (no vmcnt drain); consumers get compiler-counted vmcnt waits.
__device__ inline void barrier_lds() {
  asm volatile("s_waitcnt lgkmcnt(0)\n\ts_barrier" ::: "memory");
}

// ---------------------------------------------------------------------------
// prep: weights fp32 -> bf16 with PER-GATE ARGUMENT PRE-SCALING:
//   gates i,f,o: scale by -log2(e)  = -1.44269504
//   gate  g    : scale by -2log2(e) = -2.88539008
// so sigm(x) = rcp(1+exp2(W'x)) and tanh(g) = 2*rcp(1+exp2(W'x)) - 1 need no
// in-kernel multiply. bsum = scale*(bih+bhh).
// ---------------------------------------------------------------------------
__global__ __launch_bounds__(256) void prep_weights(
    const float* __restrict__ Wih, const float* __restrict__ Whh,
    const float* __restrict__ bih, const float* __restrict__ bhh,
    unsigned short* __restrict__ WihB, unsigned short* __restrict__ WhhB,
    float* __restrict__ bsum) {
  int tid = blockIdx.x * 256 + threadIdx.x;  // 0..65535 float4 tasks
  // row within [4][512][128] flat: 128 floats/row -> row = tid/32; gate row
  // within layer = row & 511; gate = (row & 511) >> 7.
  int gate = ((tid >> 5) & 511) >> 7;
  float s = (gate == 2) ? -2.88539008f : -1.44269504f;
  float4 a = *(const float4*)(Wih + tid * 4);
  ushort4 o;
  o.x = f2bf(a.x * s); o.y = f2bf(a.y * s); o.z = f2bf(a.z * s); o.w = f2bf(a.w * s);
  *(ushort4*)(WihB + tid * 4) = o;
  float4 b = *(const float4*)(Whh + tid * 4);
  ushort4 p;
  p.x = f2bf(b.x * s); p.y = f2bf(b.y * s); p.z = f2bf(b.z * s); p.w = f2bf(b.w * s);
  *(ushort4*)(WhhB + tid * 4) = p;
  if (tid < 2048) {
    int g2 = (tid & 511) >> 7;
    float s2 = (g2 == 2) ? -2.88539008f : -1.44269504f;
    bsum[tid] = s2 * (bih[tid] + bhh[tid]);
  }
}

// ---------------------------------------------------------------------------
// cast: xbf = bf16(x)
// ---------------------------------------------------------------------------
__global__ __launch_bounds__(256) void cast_bf(
    const float* __restrict__ x, unsigned short* __restrict__ xb) {
  int tid = blockIdx.x * 256 + threadIdx.x;
  float4 v = *(const float4*)(x + tid * 4);
  ushort4 o;
  o.x = f2bf(v.x); o.y = f2bf(v.y); o.z = f2bf(v.z); o.w = f2bf(v.w);
  *(ushort4*)(xb + tid * 4) = o;
}

// ---------------------------------------------------------------------------
// lstm_fused: WG = 80 nodes, 8 waves; wave w owns gate-cols {g*128 + w*16+l15}.
// ---------------------------------------------------------------------------
__global__ __launch_bounds__(512, 2) void lstm_fused(
    const unsigned short* __restrict__ xbf,   // [N][128] bf16
    const int* __restrict__ src,              // [E]
    const unsigned short* __restrict__ WihB,  // [512][128] bf16 (layer slice)
    const unsigned short* __restrict__ WhhB,  // [512][128] bf16
    const float* __restrict__ bsum,           // [512]
    float* __restrict__ agg) {                // [N,128] fp32
  __shared__ __align__(16) unsigned char xsb[2][NPB * 256];   // x dbuf (40KB)
  __shared__ __align__(16) unsigned char hbuf[2][NPB * 256];  // h dbuf (40KB)
  __shared__ __align__(16) int idx_s[NPB * DEG];              // [t*80 + node]
  const int tid = threadIdx.x;
  const int lane = tid & 63, w = tid >> 6;
  const int l15 = lane & 15, l4 = lane >> 4;
  const int node0 = blockIdx.x * NPB;
  const int colb = w * 16 + l15;  // this wave-lane's output column (per gate)

  // edge indices: task = node*16 + t  ->  idx_s[t*80 + node]
#pragma unroll
  for (int i = 0; i < 3; ++i) {
    int task = tid + i * 512;
    if (task < NPB * DEG) {
      int node = task >> 4, t = task & 15;
      idx_s[t * NPB + node] = src[node0 * DEG + task];
    }
  }

  // weight B-fragments (bf16, pre-scaled): B[k][n] = W[gate*128+colb][k]
  bf16x8 bwx[4][4], bwh[4][4];
  float bs[4];
#pragma unroll
  for (int g = 0; g < 4; ++g) {
#pragma unroll
    for (int kt = 0; kt < 4; ++kt) {
      bwx[g][kt] = *(const bf16x8*)(WihB + (g * 128 + colb) * 128 + kt * 32 + l4 * 8);
      bwh[g][kt] = *(const bf16x8*)(WhhB + (g * 128 + colb) * 128 + kt * 32 + l4 * 8);
    }
    bs[g] = bsum[g * 128 + colb];
  }
  barrier_lds();  // idx_s visible

  // staging tasks: task = row*16 + chunk; LDS physical chunk p holds logical
  // chunk p ^ (row&7)  (matches the XOR-swizzled read below).
  const int task0 = tid, task1 = tid + 512;
  const int row0s = task0 >> 4, ch0 = task0 & 15;
  const int row1s = task1 >> 4, ch1 = task1 & 15;
  const int task2 = tid + 1024;
  const bool p2 = task2 < NPB * 16;
  const int row2s = task2 >> 4, ch2 = task2 & 15;

  // prologue: stage x rows for t=0
  {
    uint4 v0 = *(const uint4*)(xbf + idx_s[row0s] * 128 + (ch0 ^ (row0s & 7)) * 8);
    uint4 v1 = *(const uint4*)(xbf + idx_s[row1s] * 128 + (ch1 ^ (row1s & 7)) * 8);
    *(uint4*)(&xsb[0][row0s * 256 + ch0 * 16]) = v0;
    *(uint4*)(&xsb[0][row1s * 256 + ch1 * 16]) = v1;
    if (p2) {
      uint4 v2 = *(const uint4*)(xbf + idx_s[row2s] * 128 + (ch2 ^ (row2s & 7)) * 8);
      *(uint4*)(&xsb[0][row2s * 256 + ch2 * 16]) = v2;
    }
  }
  barrier_lds();  // xsb[0] ready

  float c[RT][4];
#pragma unroll
  for (int rt = 0; rt < RT; ++rt)
#pragma unroll
    for (int r = 0; r < 4; ++r) c[rt][r] = 0.f;

#pragma unroll 2
  for (int t = 0; t < 16; ++t) {
    // (a) issue next step's x gather into regs (T14: write after compute)
    uint4 xstg0, xstg1, xstg2;
    if (t < 15) {
      const int tb = (t + 1) * NPB;
      xstg0 = *(const uint4*)(xbf + idx_s[tb + row0s] * 128 + (ch0 ^ (row0s & 7)) * 8);
      xstg1 = *(const uint4*)(xbf + idx_s[tb + row1s] * 128 + (ch1 ^ (row1s & 7)) * 8);
      if (p2)
        xstg2 = *(const uint4*)(xbf + idx_s[tb + row2s] * 128 + (ch2 ^ (row2s & 7)) * 8);
    }

    const unsigned char* xrb = xsb[t & 1];
    const unsigned char* hb = hbuf[(t + 1) & 1];  // == (t-1)&1
    unsigned char* hw = hbuf[t & 1];

    // per-rt pipelined body: acc live only within one rt
#pragma unroll
    for (int rt = 0; rt < RT; ++rt) {
      f32x4 acc[4];
#pragma unroll
      for (int g = 0; g < 4; ++g) acc[g] = (f32x4){bs[g], bs[g], bs[g], bs[g]};

      const int m = rt * 16 + l15;
      // x-part (XOR on the FULL offset — mask bits overlap kt*64 at bit 6)
#pragma unroll
      for (int kt = 0; kt < 4; ++kt) {
        int byte = (m * 256 + kt * 64 + l4 * 16) ^ ((m & 7) << 4);
        bf16x8 a = *(const bf16x8*)(xrb + byte);
#pragma unroll
        for (int g = 0; g < 4; ++g)
          acc[g] = __builtin_amdgcn_mfma_f32_16x16x32_bf16(a, bwx[g][kt], acc[g], 0, 0, 0);
      }
      // h-part (h == 0 at t==0)
      if (t > 0) {
#pragma unroll
        for (int kt = 0; kt < 4; ++kt) {
          int byte = (m * 256 + kt * 64 + l4 * 16) ^ ((m & 7) << 4);
          bf16x8 a = *(const bf16x8*)(hb + byte);
#pragma unroll
          for (int g = 0; g < 4; ++g)
            acc[g] = __builtin_amdgcn_mfma_f32_16x16x32_bf16(a, bwh[g][kt], acc[g], 0, 0, 0);
        }
      }

      // gates + state update. Weights pre-scaled: acc = -1.4427*p (i,f,o),
      // -2.8854*p (g). sigm = rcp(1+exp2(acc)); tanh = 2*rcp(1+exp2(acc))-1.
#pragma unroll
      for (int r = 0; r < 4; ++r) {
        float ig = frcp(1.f + fexp2(acc[0][r]));
        float fg = frcp(1.f + fexp2(acc[1][r]));
        float gg = 2.f * frcp(1.f + fexp2(acc[2][r])) - 1.f;
        float og = frcp(1.f + fexp2(acc[3][r]));
        float cn = fg * c[rt][r] + ig * gg;
        c[rt][r] = cn;
        float th = 2.f * frcp(1.f + fexp2(-2.88539008f * cn)) - 1.f;
        float hv = og * th;
        int mm = rt * 16 + l4 * 4 + r;
        if (t < 15) {
          int byte = (mm * 256 + colb * 2) ^ ((mm & 7) << 4);
          *(__bf16*)(hw + byte) = (__bf16)hv;
        } else {
          agg[(node0 + mm) * 128 + colb] = hv;
        }
      }
    }

    if (t < 15) {
      // write staged x for t+1 (linear; src was pre-swizzled)
      unsigned char* xw = xsb[(t + 1) & 1];
      *(uint4*)(&xw[row0s * 256 + ch0 * 16]) = xstg0;
      *(uint4*)(&xw[row1s * 256 + ch1 * 16]) = xstg1;
      if (p2) *(uint4*)(&xw[row2s * 256 + ch2 * 16]) = xstg2;
      barrier_lds();  // h_t and x_{t+1} visible; loads keep flying
    }
  }
}

// ---------------------------------------------------------------------------
// gemm_out: out[N,NOUT] = agg@Wl.T + bl + x@Wr.T (+resid) (+relu)
// One K=256 GEMM with A = [agg | x], B = [Wl | Wr]. Optionally dual-writes
// bf16 copy (next layer's gather source).
// ---------------------------------------------------------------------------
__global__ __launch_bounds__(256) void gemm_out(
    const float* __restrict__ A1,   // agg [N,128]
    const float* __restrict__ A2,   // x   [N,128]
    const float* __restrict__ Wl, const float* __restrict__ bl,
    const float* __restrict__ Wr,
    const float* __restrict__ resid,    // nullptr or [N,128]
    float* __restrict__ out,
    unsigned short* __restrict__ outbf,  // nullptr or [N,128] bf16
    int NOUT, int do_relu, int Nrows) {
  __shared__ __align__(16) unsigned char As[64 * 512];  // [64 rows][256 bf16], swizzled
  const int tid = threadIdx.x;
  const int lane = tid & 63, w = tid >> 6;
  const int l15 = lane & 15, l4 = lane >> 4;
  const int row0 = blockIdx.x * 64;

#pragma unroll
  for (int i = 0; i < 16; ++i) {
    int flat = i * 1024 + tid * 4;  // 0..16383
    int r = flat >> 8, c = flat & 255;
    int grow = row0 + r;
    float4 v;
    if (grow < Nrows)
      v = (c < 128) ? *(const float4*)(A1 + grow * 128 + c)
                    : *(const float4*)(A2 + grow * 128 + (c - 128));
    else
      v = make_float4(0.f, 0.f, 0.f, 0.f);
    ushort4 b;
    b.x = f2bf(v.x); b.y = f2bf(v.y); b.z = f2bf(v.z); b.w = f2bf(v.w);
    int byte = (r * 512 + c * 2) ^ ((r & 7) << 4);
    *(ushort4*)(As + byte) = b;
  }
  __syncthreads();

  const int colg = blockIdx.y * 64 + w * 16 + l15;
  bf16x8 bw[8];
#pragma unroll
  for (int kt = 0; kt < 8; ++kt) {
    const float* bp = (kt < 4) ? (Wl + colg * 128 + kt * 32 + l4 * 8)
                               : (Wr + colg * 128 + (kt - 4) * 32 + l4 * 8);
    float4 a = *(const float4*)bp;
    float4 b = *(const float4*)(bp + 4);
    bf16x8 v;
    v[0] = (__bf16)a.x; v[1] = (__bf16)a.y; v[2] = (__bf16)a.z; v[3] = (__bf16)a.w;
    v[4] = (__bf16)b.x; v[5] = (__bf16)b.y; v[6] = (__bf16)b.z; v[7] = (__bf16)b.w;
    bw[kt] = v;
  }

  f32x4 acc[4];
#pragma unroll
  for (int rt = 0; rt < 4; ++rt) acc[rt] = (f32x4){0.f, 0.f, 0.f, 0.f};

#pragma unroll
  for (int kt = 0; kt < 8; ++kt) {
#pragma unroll
    for (int rt = 0; rt < 4; ++rt) {
      int m = rt * 16 + l15;
      int byte = (m * 512 + kt * 64 + l4 * 16) ^ ((m & 7) << 4);
      bf16x8 af = *(const bf16x8*)(As + byte);
      acc[rt] = __builtin_amdgcn_mfma_f32_16x16x32_bf16(af, bw[kt], acc[rt], 0, 0, 0);
    }
  }

  const float bias = bl[colg];
#pragma unroll
  for (int rt = 0; rt < 4; ++rt)
#pragma unroll
    for (int r = 0; r < 4; ++r) {
      int grow = row0 + rt * 16 + l4 * 4 + r;
      if (grow < Nrows) {
        float v = acc[rt][r] + bias;
        if (resid) v += resid[grow * 128 + colg];
        if (do_relu) v = fmaxf(v, 0.f);
        out[grow * NOUT + colg] = v;
        if (outbf) outbf[grow * 128 + colg] = f2bf(v);
      }
    }
}

// ---------------------------------------------------------------------------
extern "C" void kernel_launch(void* const* d_in, const int* in_sizes, int n_in,
                              void* d_out, int out_size, void* d_ws, size_t ws_size,
                              hipStream_t stream) {
  const float* X = (const float*)d_in[0];
  const int* src = (const int*)d_in[1];  // edge_index[0] = first E ints
  const float* Wih = (const float*)d_in[2];
  const float* Whh = (const float*)d_in[3];
  const float* bih = (const float*)d_in[4];
  const float* bhh = (const float*)d_in[5];
  const float* Wl123 = (const float*)d_in[6];
  const float* bl123 = (const float*)d_in[7];
  const float* Wr123 = (const float*)d_in[8];
  const float* Wl4 = (const float*)d_in[9];
  const float* bl4 = (const float*)d_in[10];
  const float* Wr4 = (const float*)d_in[11];
  float* out = (float*)d_out;

  char* ws = (char*)d_ws;
  unsigned short* xbf = (unsigned short*)ws;                 // 5.12 MB
  float* agg = (float*)(ws + 5120000);                       // 10.24 MB
  float* xb0 = (float*)(ws + 15360000);                      // 10.24 MB
  float* xb1 = (float*)(ws + 25600000);                      // 10.24 MB
  unsigned short* WihB = (unsigned short*)(ws + 35840000);   // 0.52 MB
  unsigned short* WhhB = (unsigned short*)(ws + 36364288);   // 0.52 MB
  float* bsumW = (float*)(ws + 36888576);                    // 8 KB

  prep_weights<<<dim3(256), 256, 0, stream>>>(Wih, Whh, bih, bhh, WihB, WhhB, bsumW);
  cast_bf<<<dim3(2500), 256, 0, stream>>>(X, xbf);

  const float* xcur = X;
  for (int L = 0; L < 4; ++L) {
    lstm_fused<<<dim3(250), 512, 0, stream>>>(xbf, src, WihB + L * 65536,
                                              WhhB + L * 65536, bsumW + L * 512, agg);
    if (L < 3) {
      float* nxt = (L & 1) ? xb1 : xb0;
      gemm_out<<<dim3(313, 2), 256, 0, stream>>>(agg, xcur, Wl123 + L * 16384,
                                                 bl123 + L * 128, Wr123 + L * 16384,
                                                 (L >= 1) ? xcur : nullptr, nxt, xbf,
                                                 128, 1, N_NODES);
      xcur = nxt;
    } else {
      gemm_out<<<dim3(313, 1), 256, 0, stream>>>(agg, xcur, Wl4, bl4, Wr4, nullptr, out,
                                                 nullptr, 64, 0, N_NODES);
    }
  }
}